// Round 1
// baseline (9238.200 us; speedup 1.0000x reference)
//
#include <hip/hip_runtime.h>
#include <hip/hip_bf16.h>
#include <stdint.h>

#define LL 4096
#define EE 300
#define HH 512
#define G4H 2048
#define TT 11
#define TSTART 9
#define TSTOP 10
#define NEGINF -10000.0f

__device__ __forceinline__ float sigf(float x){
    x = fminf(fmaxf(x, -30.f), 30.f);
    return 1.0f / (1.0f + __expf(-x));
}
__device__ __forceinline__ float tanhfast(float x){
    x = fminf(fmaxf(x, -15.f), 15.f);
    float e = __expf(-2.0f * x);
    return (1.0f - e) / (1.0f + e);
}
__device__ __forceinline__ unsigned long long shfl_u64(unsigned long long v, int src){
    unsigned lo = (unsigned)v, hi = (unsigned)(v >> 32);
    lo = __shfl(lo, src, 64); hi = __shfl(hi, src, 64);
    return ((unsigned long long)hi << 32) | (unsigned long long)lo;
}

// ---------------- K0: zero the h-communication buffers (fresh tags each call)
__global__ void k0_zero(unsigned long long* __restrict__ comm){
    int i = blockIdx.x * blockDim.x + threadIdx.x;
    if (i < 2 * 2 * HH) comm[i] = 0ull;
}

// ---------------- K1: xg[dir][t][r] = emb[sent[t]] . w_ih[dir][r] + b_ih[r] + b_hh[r]
__global__ __launch_bounds__(256) void k1_xg(
    const int* __restrict__ sent, const float* __restrict__ emb,
    const float* __restrict__ wih_f, const float* __restrict__ bih_f, const float* __restrict__ bhh_f,
    const float* __restrict__ wih_b, const float* __restrict__ bih_b, const float* __restrict__ bhh_b,
    float* __restrict__ xg_f, float* __restrict__ xg_b)
{
    __shared__ float elds[32 * 304];
    int t0  = blockIdx.x * 32;
    int r0  = blockIdx.y * 128;
    int dir = blockIdx.z;
    const float* wih = dir ? wih_b : wih_f;
    const float* bih = dir ? bih_b : bih_f;
    const float* bhh = dir ? bhh_b : bhh_f;
    float* xg = dir ? xg_b : xg_f;

    for (int idx = threadIdx.x; idx < 32 * EE; idx += 256){
        int i = idx / EE, e = idx - i * EE;
        elds[i * 304 + e] = emb[(long)sent[t0 + i] * EE + e];
    }
    __syncthreads();

    int r = r0 + (threadIdx.x & 127);
    int half = threadIdx.x >> 7;
    float acc[16];
    #pragma unroll
    for (int i = 0; i < 16; i++) acc[i] = 0.f;
    const float* wrow = wih + (long)r * EE;
    for (int e4 = 0; e4 < 75; e4++){
        float4 w = *reinterpret_cast<const float4*>(wrow + e4 * 4);
        #pragma unroll
        for (int i = 0; i < 16; i++){
            float4 ev = *reinterpret_cast<const float4*>(&elds[(half * 16 + i) * 304 + e4 * 4]);
            acc[i] += w.x * ev.x + w.y * ev.y + w.z * ev.z + w.w * ev.w;
        }
    }
    float b = bih[r] + bhh[r];
    #pragma unroll
    for (int i = 0; i < 16; i++){
        xg[(long)(t0 + half * 16 + i) * G4H + r] = acc[i] + b;
    }
}

// ---------------- K2: persistent BiLSTM. 64 blocks: bid>>5 = dir, bid&31 = h-slice.
// Per block: owns j0..j0+15 of h; 64 rows of W_hh in registers (64 f32/thread).
// Sync: self-tagged u64 words (tag<<32 | f32bits(h)), relaxed agent-scope atomics.
__global__ __launch_bounds__(512) void k2_lstm(
    const float* __restrict__ whh_f, const float* __restrict__ whh_b,
    const float* __restrict__ xg_f, const float* __restrict__ xg_b,
    float* __restrict__ hs_f, float* __restrict__ hs_b,
    unsigned long long* __restrict__ comm)
{
    int dir = blockIdx.x >> 5;
    int b   = blockIdx.x & 31;
    int j0  = b * 16;
    int tid = threadIdx.x;
    int w   = tid >> 6;   // 0..7: h-segment of 64
    int l   = tid & 63;   // 0..63: row lane
    int g   = l >> 4;     // gate 0..3 (i,f,g,o)
    int jl  = l & 15;
    int row = g * HH + j0 + jl;     // 0..2047

    const float* whh = dir ? whh_b : whh_f;
    const float* xg  = dir ? xg_b  : xg_f;
    float* hs        = dir ? hs_b  : hs_f;
    unsigned long long* cm = comm + dir * 2 * HH;

    float wreg[64];
    {
        const float* wp = whh + (long)row * HH + w * 64;
        #pragma unroll
        for (int i = 0; i < 64; i += 4){
            float4 v = *reinterpret_cast<const float4*>(wp + i);
            wreg[i] = v.x; wreg[i+1] = v.y; wreg[i+2] = v.z; wreg[i+3] = v.w;
        }
    }

    __shared__ float hlds[HH];
    __shared__ float plds[8 * 64];
    float c = 0.f;

    for (int s = 0; s < LL; ++s){
        int t = dir ? (LL - 1 - s) : s;
        // prefetch this step's xg for wave 0 (overlaps with poll)
        float xgv = 0.f;
        if (tid < 64) xgv = xg[(long)t * G4H + row];

        if (s == 0){
            hlds[tid] = 0.f;
        } else {
            const unsigned long long* pw = cm + (s & 1) * HH + tid;
            unsigned long long v;
            do {
                v = __hip_atomic_load(pw, __ATOMIC_RELAXED, __HIP_MEMORY_SCOPE_AGENT);
            } while ((v >> 32) != (unsigned long long)s);
            union { unsigned u; float f; } cv; cv.u = (unsigned)v;
            hlds[tid] = cv.f;
        }
        __syncthreads();

        // partial dot over this wave's 64-wide h segment (LDS reads are wave-broadcast)
        float a0 = 0.f, a1 = 0.f, a2 = 0.f, a3 = 0.f;
        const float* hseg = &hlds[w * 64];
        #pragma unroll
        for (int i = 0; i < 64; i += 4){
            float4 hv = *reinterpret_cast<const float4*>(hseg + i);
            a0 += wreg[i]   * hv.x; a1 += wreg[i+1] * hv.y;
            a2 += wreg[i+2] * hv.z; a3 += wreg[i+3] * hv.w;
        }
        plds[w * 64 + l] = (a0 + a1) + (a2 + a3);
        __syncthreads();

        if (tid < 64){
            float sum = 0.f;
            #pragma unroll
            for (int q = 0; q < 8; q++) sum += plds[q * 64 + l];
            float pre = sum + xgv;
            // gather i,f,g,o preacts for this lane's j
            float vi = __shfl(pre, jl,      64);
            float vf = __shfl(pre, 16 + jl, 64);
            float vg = __shfl(pre, 32 + jl, 64);
            float vo = __shfl(pre, 48 + jl, 64);
            c = sigf(vf) * c + sigf(vi) * tanhfast(vg);
            float h = sigf(vo) * tanhfast(c);
            if (l < 16){
                union { float f; unsigned u; } hv2; hv2.f = h;
                unsigned long long pk = ((unsigned long long)(s + 1) << 32) | (unsigned long long)hv2.u;
                __hip_atomic_store(cm + ((s + 1) & 1) * HH + (j0 + jl), pk,
                                   __ATOMIC_RELAXED, __HIP_MEMORY_SCOPE_AGENT);
                hs[(long)t * HH + (j0 + jl)] = h;
            }
        }
        // no trailing barrier needed: other waves can only touch hlds/plds after
        // their poll succeeds, which requires our wave-0 store above.
    }
}

// ---------------- K3: feats[t][n] = w_tag[n] . [hf[t], hb[t]] + b_tag[n]
__global__ __launch_bounds__(64) void k3_feats(
    const float* __restrict__ hs_f, const float* __restrict__ hs_b,
    const float* __restrict__ wtag, const float* __restrict__ btag,
    float* __restrict__ feats)
{
    int t = blockIdx.x;
    int lane = threadIdx.x;
    float hreg[16];
    #pragma unroll
    for (int q = 0; q < 16; q++){
        int k = q * 64 + lane;
        hreg[q] = (q < 8) ? hs_f[(long)t * HH + k] : hs_b[(long)t * HH + (k - HH)];
    }
    for (int n = 0; n < TT; n++){
        float a = 0.f;
        #pragma unroll
        for (int q = 0; q < 16; q++){
            a += wtag[n * 1024 + q * 64 + lane] * hreg[q];
        }
        #pragma unroll
        for (int off = 32; off; off >>= 1) a += __shfl_down(a, off, 64);
        if (lane == 0) feats[t * 12 + n] = a + btag[n];
    }
}

// ---------------- K4: Viterbi scan + backtrace on a single wave
__global__ __launch_bounds__(64) void k4_viterbi(
    const float* __restrict__ feats, const float* __restrict__ trans,
    float* __restrict__ out)
{
    __shared__ unsigned long long bplds[LL];
    int lane = threadIdx.x;
    float tr[TT];
    #pragma unroll
    for (int p = 0; p < TT; p++) tr[p] = (lane < TT) ? trans[lane * TT + p] : NEGINF;
    float fv = (lane == TSTART) ? 0.f : NEGINF;

    #define LDF(t) ((lane < TT) ? feats[(t) * 12 + lane] : 0.f)
    float f0 = LDF(0), f1 = LDF(1), f2 = LDF(2), f3 = LDF(3);

    for (int t = 0; t < LL; t += 4){
        #define VSTEP(FT, TNEXT, TCUR) { \
            float best = __shfl(fv, 0, 64) + tr[0]; int bp = 0; \
            _Pragma("unroll") \
            for (int p = 1; p < TT; p++){ \
                float sp = __shfl(fv, p, 64) + tr[p]; \
                if (sp > best){ best = sp; bp = p; } \
            } \
            unsigned lo = (lane < 8) ? ((unsigned)bp << (4 * lane)) : 0u; \
            unsigned hi = (lane >= 8 && lane < TT) ? ((unsigned)bp << (4 * (lane - 8))) : 0u; \
            _Pragma("unroll") \
            for (int off = 1; off < 16; off <<= 1){ \
                lo |= __shfl_xor(lo, off, 16); hi |= __shfl_xor(hi, off, 16); \
            } \
            if (lane == 0) bplds[TCUR] = (unsigned long long)lo | ((unsigned long long)hi << 32); \
            fv = best + FT; \
            FT = ((TNEXT) < LL) ? LDF(TNEXT) : 0.f; \
        }
        VSTEP(f0, t + 4, t)
        VSTEP(f1, t + 5, t + 1)
        VSTEP(f2, t + 6, t + 2)
        VSTEP(f3, t + 7, t + 3)
        #undef VSTEP
    }
    __syncthreads();

    float term = (lane < TT) ? (fv + trans[TSTOP * TT + lane]) : -3.0e38f;
    int idx = (lane < TT) ? lane : 63;
    #pragma unroll
    for (int off = 32; off; off >>= 1){
        float os = __shfl_down(term, off, 64);
        int   oi = __shfl_down(idx,  off, 64);
        if (os > term || (os == term && oi < idx)){ term = os; idx = oi; }
    }
    term = __shfl(term, 0, 64);
    idx  = __shfl(idx,  0, 64);
    if (lane == 0){
        out[0] = term;                 // path_score
        out[1 + (LL - 1)] = (float)idx; // path[L-1]
    }

    // backtrace: bp table register-resident (lane holds bplds[i*64+lane]),
    // per-step value broadcast via shfl; tag chain is uniform across lanes.
    unsigned long long bpr[64];
    #pragma unroll
    for (int i = 0; i < 64; i++) bpr[i] = bplds[i * 64 + lane];
    int tag = idx;
    #pragma unroll
    for (int i = 63; i >= 0; --i){
        for (int l2 = 63; l2 >= 0; --l2){
            int u = i * 64 + l2;
            if (u == 0) break;
            unsigned long long wv = shfl_u64(bpr[i], l2);
            tag = (int)((wv >> (4 * tag)) & 15ull);
            if (lane == 0) out[u] = (float)tag;  // out[1 + (u-1)]
        }
    }
}

__global__ void k_dbg(float* out, float v){ out[0] = v; }

extern "C" void kernel_launch(void* const* d_in, const int* in_sizes, int n_in,
                              void* d_out, int out_size, void* d_ws, size_t ws_size,
                              hipStream_t stream)
{
    const int*   sent  = (const int*)  d_in[0];
    const float* emb   = (const float*)d_in[1];
    const float* wih_f = (const float*)d_in[2];
    const float* whh_f = (const float*)d_in[3];
    const float* bih_f = (const float*)d_in[4];
    const float* bhh_f = (const float*)d_in[5];
    const float* wih_b = (const float*)d_in[6];
    const float* whh_b = (const float*)d_in[7];
    const float* bih_b = (const float*)d_in[8];
    const float* bhh_b = (const float*)d_in[9];
    const float* wtag  = (const float*)d_in[10];
    const float* btag  = (const float*)d_in[11];
    const float* trans = (const float*)d_in[12];
    float* out = (float*)d_out;

    char* ws = (char*)d_ws;
    size_t off = 0;
    float* xg_f = (float*)(ws + off); off += (size_t)LL * G4H * 4;
    float* xg_b = (float*)(ws + off); off += (size_t)LL * G4H * 4;
    float* hs_f = (float*)(ws + off); off += (size_t)LL * HH * 4;
    float* hs_b = (float*)(ws + off); off += (size_t)LL * HH * 4;
    float* feats= (float*)(ws + off); off += (size_t)LL * 12 * 4;
    unsigned long long* comm = (unsigned long long*)(ws + off); off += 2 * 2 * HH * 8;

    if (off > ws_size){
        // workspace too small: write distinctive sentinel for diagnosis
        k_dbg<<<1, 1, 0, stream>>>(out, (float)ws_size);
        return;
    }

    k0_zero<<<8, 256, 0, stream>>>(comm);
    k1_xg<<<dim3(128, 16, 2), 256, 0, stream>>>(sent, emb, wih_f, bih_f, bhh_f,
                                                wih_b, bih_b, bhh_b, xg_f, xg_b);
    k2_lstm<<<64, 512, 0, stream>>>(whh_f, whh_b, xg_f, xg_b, hs_f, hs_b, comm);
    k3_feats<<<LL, 64, 0, stream>>>(hs_f, hs_b, wtag, btag, feats);
    k4_viterbi<<<1, 64, 0, stream>>>(feats, trans, out);
}